// Round 12
// baseline (2129.178 us; speedup 1.0000x reference)
//
#include <hip/hip_runtime.h>

// ---------------------------------------------------------------------------
// Bayesian LSTM forward: B=256, L=512, K=128, H=512 (4H = 2048)
//
// Base = round-6 kernel (PASSED, 1359us): 256 blocks (g 0..15 batch group of
// 16 rows, sl 0..15 slice of 32 units), 4 waves (wave = gate), LDS-staged
// A = [h | x], 20 kt x 2 col MFMAs/wave, gates dbuf, 3 barriers/step.
// Cooperative launch (accepted at this LDS/VGPR shape in r1/2/6/7) + host
// fallback to plain launch if rejected (r9/10 trap).
//
// Grafts (both individually proven):
//  - r7 publish protocol: word = pk_bf16(h0,h1) | tag, tag bits 14/30
//    (= bf16 exp MSBs, always 0 for |h|<=1), pattern = step mod 4. Consumer
//    XOR-cleans; cleaned word IS the bf16 pair -> no dequant VALU.
//    Ring-2 buffers; stale (distance 2) differs in bit 30, zero-init differs
//    for all t; distance >=4 impossible (all-to-all flow control).
//  - pre-issued 2-deep snapshot poll: S0/S1 (4x dwordx4 sc1 each) issued at
//    previous step's publish; polled alternately with counted vmcnt.
//    All loop VM ops are inline asm; steady outstanding at step top =
//    [pub(1), out(1), x(2), S0(4), S1(4)] = 12 -> vmcnt(8) = x ready,
//    vmcnt(4) = S0 ready; after any re-issue, vmcnt(4) = other set ready.
// ---------------------------------------------------------------------------

typedef __attribute__((ext_vector_type(8))) __bf16 bf16x8;
typedef __attribute__((ext_vector_type(4))) float f32x4;
typedef __attribute__((ext_vector_type(8))) unsigned short us8;
typedef __attribute__((ext_vector_type(4))) unsigned int u32x4;

union U8 { us8 v; unsigned short u[8]; };

#define WFRAG_OFF   0u           // 1310720 ushort = 2621440 B
#define HBUF_OFF    2621440u     // 2 bufs * 65536 u32 = 524288 B
#define PART_OFF    3178496u     // 512 float
#define WS_NEEDED   3180544u

#define LOSS_OFF    67108864u
#define HT_OFF      67108865u
#define CT_OFF      67239937u

#define TAGMASK 0x40004000u

__device__ __forceinline__ unsigned short f2bf(float f) {
  unsigned int u = __builtin_bit_cast(unsigned int, f);
  unsigned int r = (u + 0x7FFFu + ((u >> 16) & 1u)) >> 16;
  return (unsigned short)r;
}
__device__ __forceinline__ unsigned int pk_bf16(float a, float b) {
  unsigned int r;
  asm("v_cvt_pk_bf16_f32 %0, %1, %2" : "=v"(r) : "v"(a), "v"(b));
  return r;
}
__device__ __forceinline__ float sigm(float v) {
  return __builtin_amdgcn_rcpf(1.0f + __expf(-v));
}
__device__ __forceinline__ float tanh_f(float v) {
  return 1.0f - 2.0f * __builtin_amdgcn_rcpf(__expf(2.0f * v) + 1.0f);
}

#define BAR_LGKM() asm volatile("s_waitcnt lgkmcnt(0)\n\ts_barrier" ::: "memory")

#define MFMA(a, b, c) __builtin_amdgcn_mfma_f32_16x16x32_bf16( \
    __builtin_bit_cast(bf16x8, a), __builtin_bit_cast(bf16x8, b), c, 0, 0, 0)

// issue 64B contiguous snapshot (4 x dwordx4 sc1), NO wait
#define GISS(q0,q1,q2,q3, ptr)                                           \
  asm volatile("global_load_dwordx4 %0, %4, off sc1\n\t"                 \
               "global_load_dwordx4 %1, %4, off offset:16 sc1\n\t"       \
               "global_load_dwordx4 %2, %4, off offset:32 sc1\n\t"       \
               "global_load_dwordx4 %3, %4, off offset:48 sc1"           \
               : "+v"(q0), "+v"(q1), "+v"(q2), "+v"(q3)                  \
               : "v"(ptr) : "memory")
// older snapshot complete (exactly the 4 newest loads may remain)
#define WAIT4(q0,q1,q2,q3)                                               \
  asm volatile("s_waitcnt vmcnt(4)"                                      \
               : "+v"(q0),"+v"(q1),"+v"(q2),"+v"(q3) :: "memory")
// stores + x prefetch complete (both snapshot sets may remain)
#define WAIT8X(xa,xb)                                                    \
  asm volatile("s_waitcnt vmcnt(8)" : "+v"(xa),"+v"(xb) :: "memory")
// x prefetch: 2 x dwordx4 fp32
#define XISS(xa,xb, ptr)                                                 \
  asm volatile("global_load_dwordx4 %0, %2, off\n\t"                     \
               "global_load_dwordx4 %1, %2, off offset:16"               \
               : "+v"(xa), "+v"(xb) : "v"(ptr) : "memory")
#define STD(p_, v_)  asm volatile("global_store_dword %0, %1, off sc1"   \
               :: "v"(p_), "v"(v_) : "memory")
#define STDF(p_, f_) asm volatile("global_store_dword %0, %1, off"       \
               :: "v"(p_), "v"(f_) : "memory")
#define STD2(p_, v_) asm volatile("global_store_dwordx2 %0, %1, off"     \
               :: "v"(p_), "v"(v_) : "memory")

// ---------------- prep: weight fragments (r6 layout) + ring zero ------------
__global__ void prep_w(const float* __restrict__ whh, const float* __restrict__ wih,
                       unsigned short* __restrict__ w_frag,
                       unsigned int* __restrict__ h_words) {
  int gid = blockIdx.x * 256 + threadIdx.x;
  if (gid < 131072) h_words[gid] = 0;          // tag 00: stale can't validate
  if (gid >= 163840) return;
  int lane = gid & 63;
  int t3 = gid >> 6;
  int fr = t3 % 40;
  int w  = (t3 / 40) & 3;
  int s  = t3 / 160;
  int kt = fr % 20, ct = fr / 20;
  int gc = (w << 9) + (s << 5) + (ct << 4) + (lane & 15);
  int kbase = (kt << 5) + ((lane >> 4) << 3);
  U8 p;
#pragma unroll
  for (int j = 0; j < 8; ++j) {
    int k = kbase + j;
    float v = (k < 512) ? whh[k * 2048 + gc] : wih[(k - 512) * 2048 + gc];
    p.u[j] = f2bf(v);
  }
  *(us8*)&w_frag[(size_t)gid * 8] = p.v;
}

// ---------------- bayes loss: block partials ---------------------------------
__global__ void loss_k(const float* __restrict__ whh, const float* __restrict__ wih,
                       const float* __restrict__ bias,
                       const float* __restrict__ whh_mu, const float* __restrict__ whh_rho,
                       const float* __restrict__ wih_mu, const float* __restrict__ wih_rho,
                       const float* __restrict__ b_mu, const float* __restrict__ b_rho,
                       float* __restrict__ partials) {
  int gid = blockIdx.x * 256 + threadIdx.x;
  float acc = 0.f;
  for (int idx = gid; idx < 1312768; idx += 131072) {
    float p, mu, rho;
    if (idx < 1048576)      { p = whh[idx];           mu = whh_mu[idx];           rho = whh_rho[idx]; }
    else if (idx < 1310720) { int i = idx - 1048576;  p = wih[i]; mu = wih_mu[i]; rho = wih_rho[i]; }
    else                    { int i = idx - 1310720;  p = bias[i]; mu = b_mu[i];  rho = b_rho[i]; }
    float sig = log1pf(__expf(rho));
    float d = p - mu;
    float vari = -0.57236494f - logf(sig) - d * d / (2.f * sig * sig);
    float lp1 = -0.91893853f - 0.5f * p * p;
    float lp2 = 5.98881675f - 500000.f * p * p;
    float prior = logf(0.5f * (__expf(lp1) + __expf(lp2)));
    acc += vari - prior;
  }
#pragma unroll
  for (int off = 32; off; off >>= 1) acc += __shfl_down(acc, off, 64);
  __shared__ float wsum[4];
  if ((threadIdx.x & 63) == 0) wsum[threadIdx.x >> 6] = acc;
  __syncthreads();
  if (threadIdx.x == 0) partials[blockIdx.x] = wsum[0] + wsum[1] + wsum[2] + wsum[3];
}

// ---------------- persistent LSTM kernel (r6 body + grafts) ------------------
__launch_bounds__(256, 1)
__global__ void lstm_k(const float* __restrict__ x,
                       const unsigned short* __restrict__ w_frag,
                       const float* __restrict__ bias,
                       unsigned int* __restrict__ h_words,
                       const float* __restrict__ partials,
                       float* __restrict__ out) {
  __shared__ unsigned short A_sh[16][648];     // [row][k] h(0..511)|x(512..639)
  __shared__ float gates_sh[2][16][132];       // double-buffered epilogue

  const int tid  = threadIdx.x;
  const int lane = tid & 63;
  const int wv   = tid >> 6;                   // gate chunk (i,f,g,o)
  const int bid  = blockIdx.x;
  const int grp = ((bid & 7) << 1) | ((bid >> 3) & 1);   // batch group 0..15
  const int s   = bid >> 4;                              // hidden slice 0..15
  const int b0 = grp << 4;

  // ---- loss finalize FIRST (independent of LSTM; self-diagnosing) ---------
  if (bid == 0) {
    float v = partials[tid] + partials[tid + 256];
#pragma unroll
    for (int off = 32; off; off >>= 1) v += __shfl_down(v, off, 64);
    __shared__ float lw[4];
    if ((tid & 63) == 0) lw[tid >> 6] = v;
    __syncthreads();
    if (tid == 0) out[LOSS_OFF] = lw[0] + lw[1] + lw[2] + lw[3];
  }

  // ---- stationary B fragments: 40 x bf16x8 (r6 layout) --------------------
  us8 bfr[40];
  {
    const us8* wfp = (const us8*)(w_frag + (size_t)s * 81920);
#pragma unroll
    for (int fr = 0; fr < 40; ++fr)
      bfr[fr] = wfp[(wv * 40 + fr) * 64 + lane];
  }

  // ---- bias folded into accumulator init (C col = lane&15) ----------------
  const float bv0 = bias[(wv << 9) + (s << 5) + (lane & 15)];
  const float bv1 = bias[(wv << 9) + (s << 5) + 16 + (lane & 15)];

  // ---- epilogue mapping: thread -> (row r, units uo, uo+1) ----------------
  const int r  = tid >> 4;
  const int uo = (tid & 15) << 1;
  const int ug = (s << 5) + uo;
  float c0 = 0.f, c1 = 0.f;

  const unsigned short* arow = &A_sh[lane & 15][(lane >> 4) << 3];

  // ---- comm word pointers (r6 layout) -------------------------------------
  // word(buf,grp,row,pair) = buf*65536 + (grp<<12) + (row<<8) + (sl<<4) + up
  const unsigned gb = (grp << 12) + ((tid >> 4) << 8) + ((tid & 15) << 4);
  const unsigned* gp0 = h_words + gb;
  const unsigned* gp1 = h_words + 65536 + gb;
  const unsigned pb = (grp << 12) + (r << 8) + (s << 4) + (tid & 15);
  unsigned* pp0 = h_words + pb;
  unsigned* pp1 = h_words + 65536 + pb;

  const int xrow = tid >> 4;
  const int f8 = (tid & 15) << 3;
  const float* xbase = x + (((size_t)(b0 + xrow)) << 16) + f8;
  float* op = out + ((size_t)(b0 + r) << 18) + ug;

  u32x4 s00 = {0,0,0,0}, s01 = {0,0,0,0}, s02 = {0,0,0,0}, s03 = {0,0,0,0};
  u32x4 s10 = {0,0,0,0}, s11 = {0,0,0,0}, s12 = {0,0,0,0}, s13 = {0,0,0,0};
  f32x4 xr0 = {0,0,0,0}, xr1 = {0,0,0,0};

  // drain all compiler prologue VM ops so asm vmcnt counting is exact
  asm volatile("s_waitcnt vmcnt(0) lgkmcnt(0)" ::: "memory");
  XISS(xr0, xr1, xbase);                       // x for t=0
  asm volatile("s_waitcnt vmcnt(0)" : "+v"(xr0), "+v"(xr1) :: "memory");

  for (int t = 0; t < 512; ++t) {
    // ---- stage x_t (stores+x of prev iter drained; snapshots stay in flight)
    WAIT8X(xr0, xr1);
    {
      u32x4 xv;
      xv[0] = pk_bf16(xr0[0], xr0[1]); xv[1] = pk_bf16(xr0[2], xr0[3]);
      xv[2] = pk_bf16(xr1[0], xr1[1]); xv[3] = pk_bf16(xr1[2], xr1[3]);
      *(u32x4*)&A_sh[xrow][512 + f8] = xv;
    }
    BAR_LGKM();                                        // B1: x staged

    // ---- x-part MFMAs (overlap snapshot flight time) ----------------------
    f32x4 a0a = {bv0, bv0, bv0, bv0}, a0b = {0.f, 0.f, 0.f, 0.f};
    f32x4 a1a = {bv1, bv1, bv1, bv1}, a1b = {0.f, 0.f, 0.f, 0.f};
    {
      us8 xa0 = *(const us8*)(arow + (16 << 5));
      us8 xa1 = *(const us8*)(arow + (17 << 5));
      us8 xa2 = *(const us8*)(arow + (18 << 5));
      us8 xa3 = *(const us8*)(arow + (19 << 5));
      a0a = MFMA(xa0, bfr[16], a0a);
      a1a = MFMA(xa0, bfr[36], a1a);
      a0b = MFMA(xa1, bfr[17], a0b);
      a1b = MFMA(xa1, bfr[37], a1b);
      a0a = MFMA(xa2, bfr[18], a0a);
      a1a = MFMA(xa2, bfr[38], a1a);
      a0b = MFMA(xa3, bfr[19], a0b);
      a1b = MFMA(xa3, bfr[39], a1b);
    }

    if (t > 0) {
      // ---- 2-deep pre-issued poll; cleaned snapshot == staged bf16 h ------
      const unsigned pat = (((unsigned)t & 1u) << 14) |
                           ((((unsigned)t >> 1) & 1u) << 30);
      const u32x4 ps = {pat, pat, pat, pat};
      const unsigned* gp = (t & 1) ? gp1 : gp0;
      u32x4 f0, f1, f2, f3;
      for (;;) {
        WAIT4(s00, s01, s02, s03);
        u32x4 d0 = s00 ^ ps, d1 = s01 ^ ps, d2 = s02 ^ ps, d3 = s03 ^ ps;
        u32x4 o4 = (d0 | d1) | (d2 | d3);
        unsigned orr = (o4[0] | o4[1]) | (o4[2] | o4[3]);
        if (__all((orr & TAGMASK) == 0u)) { f0 = d0; f1 = d1; f2 = d2; f3 = d3; break; }
        GISS(s00, s01, s02, s03, gp);
        WAIT4(s10, s11, s12, s13);
        d0 = s10 ^ ps; d1 = s11 ^ ps; d2 = s12 ^ ps; d3 = s13 ^ ps;
        o4 = (d0 | d1) | (d2 | d3);
        orr = (o4[0] | o4[1]) | (o4[2] | o4[3]);
        if (__all((orr & TAGMASK) == 0u)) { f0 = d0; f1 = d1; f2 = d2; f3 = d3; break; }
        GISS(s10, s11, s12, s13, gp);
      }
      // thread owns row (tid>>4), units [32*(tid&15), +32): straight stores
      unsigned short* dst = &A_sh[tid >> 4][(tid & 15) << 5];
      *(u32x4*)dst        = f0;
      *(u32x4*)(dst + 8)  = f1;
      *(u32x4*)(dst + 16) = f2;
      *(u32x4*)(dst + 24) = f3;
      BAR_LGKM();                                      // B2: h staged

      // ---- h-part GEMM: 16 kt x 2 cols, 4-way acc split (r6) --------------
      us8 areg[16];
#pragma unroll
      for (int kt = 0; kt < 16; ++kt)
        areg[kt] = *(const us8*)(arow + (kt << 5));
#pragma unroll
      for (int kt = 0; kt < 16; kt += 2) {
        a0a = MFMA(areg[kt],     bfr[kt],      a0a);
        a1a = MFMA(areg[kt],     bfr[20 + kt], a1a);
        a0b = MFMA(areg[kt + 1], bfr[kt + 1],  a0b);
        a1b = MFMA(areg[kt + 1], bfr[21 + kt], a1b);
      }
    }

    // ---- combine + scatter gates (r6) -------------------------------------
    {
      f32x4 acc0 = a0a + a0b;
      f32x4 acc1 = a1a + a1b;
      const int crow = (lane >> 4) << 2;
      const int ccol = lane & 15;
#pragma unroll
      for (int q = 0; q < 4; ++q) {
        gates_sh[t & 1][crow + q][(wv << 5) + ccol]      = acc0[q];
        gates_sh[t & 1][crow + q][(wv << 5) + 16 + ccol] = acc1[q];
      }
    }
    BAR_LGKM();                                        // B3: gates ready

    // ---- gate math (r6) ----------------------------------------------------
    float2 vi = *(const float2*)&gates_sh[t & 1][r][uo];
    float2 vf = *(const float2*)&gates_sh[t & 1][r][32 + uo];
    float2 vg = *(const float2*)&gates_sh[t & 1][r][64 + uo];
    float2 vo = *(const float2*)&gates_sh[t & 1][r][96 + uo];
    float it0 = sigm(vi.x), ft0 = sigm(vf.x), ot0 = sigm(vo.x);
    c0 = ft0 * c0 + it0 * tanh_f(vg.x);
    float h0 = ot0 * tanh_f(c0);
    float it1 = sigm(vi.y), ft1 = sigm(vf.y), ot1 = sigm(vo.y);
    c1 = ft1 * c1 + it1 * tanh_f(vg.y);
    float h1 = ot1 * tanh_f(c1);

    // ---- publish tagged word + out + next-step prefetch/snapshots ---------
    {
      const unsigned T = (unsigned)(t + 1);
      const unsigned patP = ((T & 1u) << 14) | (((T >> 1) & 1u) << 30);
      unsigned word = pk_bf16(h0, h1) | patP;
      STD((T & 1u) ? pp1 : pp0, word);
      float2 hv; hv.x = h0; hv.y = h1;
      STD2(op + (size_t)t * 512, hv);
      if (t < 511) {
        XISS(xr0, xr1, xbase + (size_t)(t + 1) * 128);
        const unsigned* gpn = ((t + 1) & 1) ? gp1 : gp0;
        GISS(s00, s01, s02, s03, gpn);
        GISS(s10, s11, s12, s13, gpn);
      } else {
        float* hp = out + HT_OFF + ((size_t)(b0 + r) << 9) + ug;
        float* cp = out + CT_OFF + ((size_t)(b0 + r) << 9) + ug;
        STDF(hp, h0); STDF(hp + 1, h1);
        STDF(cp, c0); STDF(cp + 1, c1);
      }
    }
  }
  // drain in-flight ops before exit
  asm volatile("s_waitcnt vmcnt(0)"
               : "+v"(s00), "+v"(s01), "+v"(s02), "+v"(s03),
                 "+v"(s10), "+v"(s11), "+v"(s12), "+v"(s13) :: "memory");
}

// ---------------------------------------------------------------------------
extern "C" void kernel_launch(void* const* d_in, const int* in_sizes, int n_in,
                              void* d_out, int out_size, void* d_ws, size_t ws_size,
                              hipStream_t stream) {
  if (ws_size < WS_NEEDED) return;
  const float* x       = (const float*)d_in[0];
  const float* whh     = (const float*)d_in[1];
  const float* wih     = (const float*)d_in[2];
  const float* bias    = (const float*)d_in[3];
  const float* whh_mu  = (const float*)d_in[4];
  const float* whh_rho = (const float*)d_in[5];
  const float* wih_mu  = (const float*)d_in[6];
  const float* wih_rho = (const float*)d_in[7];
  const float* b_mu    = (const float*)d_in[8];
  const float* b_rho   = (const float*)d_in[9];
  char* ws = (char*)d_ws;
  unsigned short* w_frag  = (unsigned short*)(ws + WFRAG_OFF);
  unsigned int*   h_words = (unsigned int*)(ws + HBUF_OFF);
  float*          parts   = (float*)(ws + PART_OFF);
  float*          out     = (float*)d_out;

  prep_w<<<640, 256, 0, stream>>>(whh, wih, w_frag, h_words);
  loss_k<<<512, 256, 0, stream>>>(whh, wih, bias, whh_mu, whh_rho,
                                  wih_mu, wih_rho, b_mu, b_rho, parts);

  void* kargs[6];
  kargs[0] = (void*)&x;
  kargs[1] = (void*)&w_frag;
  kargs[2] = (void*)&bias;
  kargs[3] = (void*)&h_words;
  kargs[4] = (void*)&parts;
  kargs[5] = (void*)&out;
  hipError_t err = hipLaunchCooperativeKernel((const void*)lstm_k, dim3(256),
                                              dim3(256), kargs, 0, stream);
  if (err != hipSuccess) {
    // silent-rejection trap (r9/r10): fall back to plain launch.
    // Co-residency by capacity: 256 blocks, 1 block/CU on 256 CUs.
    lstm_k<<<dim3(256), dim3(256), 0, stream>>>(x, w_frag, bias, h_words,
                                                parts, out);
  }
}